// Round 14
// baseline (297.586 us; speedup 1.0000x reference)
//
#include <hip/hip_runtime.h>
#include <hip/hip_bf16.h>

// LoRALinear with NF4 base: out = x @ W^T + (alpha/rank) * (x@A^T)@B^T
//  Fold: W_eff[o][i] = NF4[codes[o][i]] * scales[o][i/64] + 2 * sum_r B[o][r]*A[r][i]
//  One bf16 GEMM: out[M=8192][N=4096] = xb[M][K=4096] . W_eff[N][K]^T
//
// GEMM: m201-structure port. 256x256 tile, BK=64, 8 phases / 2 K-tiles.
// Phase = { [vmcnt(5) @odd]; ds_reads for THIS phase; 1 STG (region that died
// last phase); BAR1; lgkm(0)+sched_barrier; setprio1; 16 MFMA; setprio0; BAR2 }.
// Region-lifetime audit: reads per phase P1:{A0a x8,B0a x2} P2:{B0a x2}
// P3:{A0b,B0b} P4:{B0b} P5-P8 mirror slot1. Stage rotation P1..P8 =
// B1b(t2i+1), A0a,B0a,A0b,B0b(t2i+2), A1a,B1a,A1b(t2i+3) - each target dead
// since prev phase's BAR2. vmcnt(5)@P1/P3/P5/P7 drains exactly the 2 regions
// first-read that phase (staged 6-7 phases ago, ~5000cy lead, no stall).
// Iter-31 stages wrap &63 into dead regions (benign). Swizzle: R1-verified
// chunk-XOR, 0 conflicts.

#define IN_DIM  4096
#define OUT_DIM 4096
#define RANK    16
#define M_TOK   8192
#define LORA_SCALE 2.0f

typedef __bf16 bf16_t;
typedef bf16_t bf16x8 __attribute__((ext_vector_type(8)));
typedef float  f32x4  __attribute__((ext_vector_type(4)));

__device__ __constant__ float NF4_TAB[16] = {
    -1.0f, -0.6961928009986877f, -0.5250730514526367f, -0.39491748809814453f,
    -0.28444138169288635f, -0.18477343022823334f, -0.09105003625154495f, 0.0f,
    0.07958029955625534f, 0.16093020141124725f, 0.24611230194568634f,
    0.33791524171829224f, 0.44070982933044434f, 0.5626170039176941f,
    0.7229568362236328f, 1.0f};

// ------------------------------------------- prep W_eff + cast x (merged)
__global__ __launch_bounds__(256) void prep_all(
    const float* __restrict__ x,
    const int* __restrict__ codes, const float* __restrict__ scales,
    const float* __restrict__ la, const float* __restrict__ lb,
    bf16_t* __restrict__ W, bf16_t* __restrict__ xb)
{
    const int tid = threadIdx.x;
    if (blockIdx.x < 1024) {
        __shared__ float nf4s[16];
        __shared__ float lbs[4][16];
        const int o0 = blockIdx.x * 4;
        if (tid < 64) lbs[tid >> 4][tid & 15] = lb[(o0 + (tid >> 4)) * RANK + (tid & 15)] * LORA_SCALE;
        else if (tid < 80) nf4s[tid - 64] = NF4_TAB[tid - 64];
        __syncthreads();

        #pragma unroll
        for (int it = 0; it < 2; ++it) {
            const int i0 = (it * 256 + tid) * 8;
            float w[4][8];
            #pragma unroll
            for (int oo = 0; oo < 4; ++oo) {
                const size_t base = (size_t)(o0 + oo) * IN_DIM + i0;
                int4 c0 = *(const int4*)(codes + base);
                int4 c1 = *(const int4*)(codes + base + 4);
                const float sc = scales[(o0 + oo) * (IN_DIM / 64) + (i0 >> 6)];
                w[oo][0] = nf4s[c0.x] * sc; w[oo][1] = nf4s[c0.y] * sc;
                w[oo][2] = nf4s[c0.z] * sc; w[oo][3] = nf4s[c0.w] * sc;
                w[oo][4] = nf4s[c1.x] * sc; w[oo][5] = nf4s[c1.y] * sc;
                w[oo][6] = nf4s[c1.z] * sc; w[oo][7] = nf4s[c1.w] * sc;
            }
            #pragma unroll
            for (int r = 0; r < RANK; ++r) {
                float4 a0 = *(const float4*)(la + r * IN_DIM + i0);
                float4 a1 = *(const float4*)(la + r * IN_DIM + i0 + 4);
                #pragma unroll
                for (int oo = 0; oo < 4; ++oo) {
                    const float b = lbs[oo][r];
                    w[oo][0] += b * a0.x; w[oo][1] += b * a0.y;
                    w[oo][2] += b * a0.z; w[oo][3] += b * a0.w;
                    w[oo][4] += b * a1.x; w[oo][5] += b * a1.y;
                    w[oo][6] += b * a1.z; w[oo][7] += b * a1.w;
                }
            }
            #pragma unroll
            for (int oo = 0; oo < 4; ++oo) {
                bf16x8 v;
                #pragma unroll
                for (int j = 0; j < 8; ++j) v[j] = (bf16_t)w[oo][j];
                *(bf16x8*)(W + (size_t)(o0 + oo) * IN_DIM + i0) = v;
            }
        }
    } else {
        const int bid = blockIdx.x - 1024;
        const int n8 = (M_TOK * IN_DIM) / 8;
        const int stride = 2048 * 256;
        for (int i = bid * 256 + tid; i < n8; i += stride) {
            const size_t e = (size_t)i * 8;
            float4 a = *(const float4*)(x + e);
            float4 b = *(const float4*)(x + e + 4);
            bf16x8 v;
            v[0] = (bf16_t)a.x; v[1] = (bf16_t)a.y; v[2] = (bf16_t)a.z; v[3] = (bf16_t)a.w;
            v[4] = (bf16_t)b.x; v[5] = (bf16_t)b.y; v[6] = (bf16_t)b.z; v[7] = (bf16_t)b.w;
            *(bf16x8*)(xb + e) = v;
        }
    }
}

// ---------------------------------------------------------------- GEMM
__global__ __launch_bounds__(512, 2) void gemm_bt(
    const bf16_t* __restrict__ A, const bf16_t* __restrict__ B,
    float* __restrict__ C)
{
    // [slot(2)][A|B][khalf(2)] 16KB regions = 128 KiB
    __shared__ __align__(128) char lds[131072];

    const int tid  = threadIdx.x;
    const int wave = tid >> 6;
    const int lane = tid & 63;

    const int flat = blockIdx.y * gridDim.x + blockIdx.x;     // 0..511
    const int swz  = (flat & 7) * 64 + (flat >> 3);           // XCD swizzle
    const int bx = swz & 15;
    const int by = swz >> 4;
    const int m0 = by * 256;
    const int n0 = bx * 256;

    const int wr = wave >> 2;         // 0..1
    const int wc = wave & 3;          // 0..3

    f32x4 acc[8][4];
    #pragma unroll
    for (int i = 0; i < 8; ++i)
        #pragma unroll
        for (int j = 0; j < 4; ++j) acc[i][j] = (f32x4)0.0f;

    const int frow = lane & 15;
    const int fch  = lane >> 4;
    const int fxor = (fch ^ ((frow >> 1) & 3)) << 4;   // R1-verified swizzle
    const int aoff = (wr * 128 + frow) * 64 + fxor;    // A frag f: +f*1024
    const int boff = (wc * 64  + frow) * 64 + fxor;    // B (nh,j): +nh*2048+j*1024

    // staging addressing: 2 x 16B per thread per 16KB region
    const int d0 = tid * 16, d1 = 8192 + tid * 16;
    const int sr0 = d0 >> 6, sr1 = d1 >> 6;
    const int sg0 = ((d0 >> 4) & 3) ^ ((sr0 >> 1) & 3);
    const int sg1 = ((d1 >> 4) & 3) ^ ((sr1 >> 1) & 3);
    const char* gA = (const char*)A;
    const char* gB = (const char*)B;

    bf16x8 fA[8], fB[2];

#define RD_A8(SL, KH) do {                                                     \
    const char* b_ = lds + (SL) * 65536 + (KH) * 16384;                        \
    _Pragma("unroll")                                                          \
    for (int f_ = 0; f_ < 8; ++f_)                                             \
        fA[f_] = *(const bf16x8*)(b_ + aoff + f_ * 1024);                      \
} while (0)

#define RD_B2(SL, KH, NH) do {                                                 \
    const char* b_ = lds + (SL) * 65536 + 32768 + (KH) * 16384;                \
    fB[0] = *(const bf16x8*)(b_ + boff + (NH) * 2048);                         \
    fB[1] = *(const bf16x8*)(b_ + boff + (NH) * 2048 + 1024);                  \
} while (0)

#define STG1(OPI, KH_, SL, T) do {                                             \
    const char* g_  = (OPI) ? gB : gA;                                         \
    const int   r0_ = (OPI) ? n0 : m0;                                         \
    const size_t ko_ = (size_t)(T) * 128 + (KH_) * 64;                         \
    const char* s0_ = g_ + (size_t)(r0_ + sr0) * 8192 + ko_ + (sg0 << 4);      \
    const char* s1_ = g_ + (size_t)(r0_ + sr1) * 8192 + ko_ + (sg1 << 4);      \
    char* db_ = lds + (SL) * 65536 + (OPI) * 32768 + (KH_) * 16384 + wave * 1024; \
    __builtin_amdgcn_global_load_lds(                                          \
        (const __attribute__((address_space(1))) void*)s0_,                    \
        (__attribute__((address_space(3))) void*)db_, 16, 0, 0);               \
    __builtin_amdgcn_global_load_lds(                                          \
        (const __attribute__((address_space(1))) void*)s1_,                    \
        (__attribute__((address_space(3))) void*)(db_ + 8192), 16, 0, 0);      \
} while (0)

#define MM16(NH) do {                                                          \
    __builtin_amdgcn_s_setprio(1);                                             \
    _Pragma("unroll")                                                          \
    for (int f_ = 0; f_ < 8; ++f_) {                                           \
        acc[f_][(NH) * 2 + 0] = __builtin_amdgcn_mfma_f32_16x16x32_bf16(       \
            fA[f_], fB[0], acc[f_][(NH) * 2 + 0], 0, 0, 0);                    \
        acc[f_][(NH) * 2 + 1] = __builtin_amdgcn_mfma_f32_16x16x32_bf16(       \
            fA[f_], fB[1], acc[f_][(NH) * 2 + 1], 0, 0, 0);                    \
    }                                                                          \
    __builtin_amdgcn_s_setprio(0);                                             \
} while (0)

// phase (m201 structure): [vmcnt(5)]; reads; STG; BAR1; lgkm(0)+SB0; MFMA; BAR2
#define PHASE(VM, SOP, SKH, SSL, ST, NH, RDS) do {                             \
    if (VM) { asm volatile("s_waitcnt vmcnt(5)" ::: "memory"); }               \
    RDS;                                                                       \
    STG1(SOP, SKH, SSL, ST);                                                   \
    __builtin_amdgcn_s_barrier();                                              \
    asm volatile("s_waitcnt lgkmcnt(0)" ::: "memory");                         \
    __builtin_amdgcn_sched_barrier(0);                                         \
    MM16(NH);                                                                  \
    __builtin_amdgcn_s_barrier();                                              \
} while (0)

    // ---- prologue: stage tiles 0 (slot0: A0a,B0a,A0b,B0b) and 1 (slot1)
    STG1(0, 0, 0, 0); STG1(1, 0, 0, 0); STG1(0, 1, 0, 0); STG1(1, 1, 0, 0);
    STG1(0, 0, 1, 1); STG1(1, 0, 1, 1); STG1(0, 1, 1, 1); STG1(1, 1, 1, 1);
    asm volatile("s_waitcnt vmcnt(0)" ::: "memory");
    __builtin_amdgcn_s_barrier();

    // ---- main loop: iter i computes K-tiles 2i (slot0, P1-P4), 2i+1 (slot1)
    for (int i = 0; i < 32; ++i) {
        const int tO  = (2 * i + 1) & 63;   // current odd tile (B1b re/stage)
        const int tE2 = (2 * i + 2) & 63;   // next even tile -> slot0
        const int tO2 = (2 * i + 3) & 63;   // next odd tile  -> slot1
        // P1: k0,n0 of even tile; stage B1b(tO)
        PHASE(1, 1, 1, 1, tO,  0, RD_A8(0, 0); RD_B2(0, 0, 0));
        // P2: k0,n1; stage A0a(tE2)
        PHASE(0, 0, 0, 0, tE2, 1, RD_B2(0, 0, 1));
        // P3: k1,n0; stage B0a(tE2)
        PHASE(1, 1, 0, 0, tE2, 0, RD_A8(0, 1); RD_B2(0, 1, 0));
        // P4: k1,n1; stage A0b(tE2)
        PHASE(0, 0, 1, 0, tE2, 1, RD_B2(0, 1, 1));
        // P5: k0,n0 of odd tile; stage B0b(tE2)
        PHASE(1, 1, 1, 0, tE2, 0, RD_A8(1, 0); RD_B2(1, 0, 0));
        // P6: k0,n1; stage A1a(tO2)
        PHASE(0, 0, 0, 1, tO2, 1, RD_B2(1, 0, 1));
        // P7: k1,n0; stage B1a(tO2)
        PHASE(1, 1, 0, 1, tO2, 0, RD_A8(1, 1); RD_B2(1, 1, 0));
        // P8: k1,n1; stage A1b(tO2)
        PHASE(0, 0, 1, 1, tO2, 1, RD_B2(1, 1, 1));
    }

    // ---- C write: D layout col=lane&15, row=(lane>>4)*4+reg [m89-verified]
    const int crow = (lane >> 4) * 4;
    const int ccol = lane & 15;
    #pragma unroll
    for (int i = 0; i < 8; ++i) {
        #pragma unroll
        for (int j = 0; j < 4; ++j) {
            const int mb = m0 + wr * 128 + i * 16 + crow;
            const int nb = n0 + wc * 64 + j * 16 + ccol;
            #pragma unroll
            for (int r = 0; r < 4; ++r)
                C[(size_t)(mb + r) * OUT_DIM + nb] = acc[i][j][r];
        }
    }
#undef RD_A8
#undef RD_B2
#undef STG1
#undef MM16
#undef PHASE
}

// ---------------------------------------------------------------- launch
extern "C" void kernel_launch(void* const* d_in, const int* in_sizes, int n_in,
                              void* d_out, int out_size, void* d_ws, size_t ws_size,
                              hipStream_t stream) {
    const float* x      = (const float*)d_in[0];
    const int*   codes  = (const int*)d_in[1];
    const float* scales = (const float*)d_in[2];
    const float* la     = (const float*)d_in[3];
    const float* lb     = (const float*)d_in[4];
    float* out = (float*)d_out;

    bf16_t* W  = (bf16_t*)d_ws;
    bf16_t* xb = (bf16_t*)((char*)d_ws + (size_t)OUT_DIM * IN_DIM * 2);

    prep_all<<<1024 + 2048, 256, 0, stream>>>(x, codes, scales, la, lb, W, xb);

    dim3 grid(OUT_DIM / 256, M_TOK / 256);   // (16, 32) = 512 blocks
    gemm_bt<<<grid, 512, 0, stream>>>(xb, W, out);
}

// Round 16
// 283.436 us; speedup vs baseline: 1.0499x; 1.0499x over previous
//
#include <hip/hip_runtime.h>
#include <hip/hip_bf16.h>

// LoRALinear with NF4 base: out = x @ W^T + (alpha/rank) * (x@A^T)@B^T
//  Fold: W_eff[o][i] = NF4[codes[o][i]] * scales[o][i/64] + 2 * sum_r B[o][r]*A[r][i]
//  One bf16 GEMM: out[M=8192][N=4096] = xb[M][K=4096] . W_eff[N][K]^T
//
// GEMM: R9 structure — measured optimum of this family (216us, 1274 TF,
// MfmaUtil 61.6%, 0 conflicts). 256x256 tile, BK=64, 8 phases, 16x16x32
// MFMA, next-phase reads interleaved into the MFMA cluster (E/O reg sets),
// 1 STG/phase, ONE barrier/phase, no explicit lgkm drain (compiler counted
// waits), vmcnt(6) at odd-phase ends. Prep: nontemporal loads for read-once
// inputs (via ext_vector types — builtin rejects HIP_vector_type).

#define IN_DIM  4096
#define OUT_DIM 4096
#define RANK    16
#define M_TOK   8192
#define LORA_SCALE 2.0f

typedef __bf16 bf16_t;
typedef bf16_t bf16x8 __attribute__((ext_vector_type(8)));
typedef float  f32x4  __attribute__((ext_vector_type(4)));
typedef int    i32x4  __attribute__((ext_vector_type(4)));

__device__ __constant__ float NF4_TAB[16] = {
    -1.0f, -0.6961928009986877f, -0.5250730514526367f, -0.39491748809814453f,
    -0.28444138169288635f, -0.18477343022823334f, -0.09105003625154495f, 0.0f,
    0.07958029955625534f, 0.16093020141124725f, 0.24611230194568634f,
    0.33791524171829224f, 0.44070982933044434f, 0.5626170039176941f,
    0.7229568362236328f, 1.0f};

// ------------------------------------------- prep W_eff + cast x (merged)
__global__ __launch_bounds__(256) void prep_all(
    const float* __restrict__ x,
    const int* __restrict__ codes, const float* __restrict__ scales,
    const float* __restrict__ la, const float* __restrict__ lb,
    bf16_t* __restrict__ W, bf16_t* __restrict__ xb)
{
    const int tid = threadIdx.x;
    if (blockIdx.x < 1024) {
        __shared__ float nf4s[16];
        __shared__ float lbs[4][16];
        const int o0 = blockIdx.x * 4;
        if (tid < 64) lbs[tid >> 4][tid & 15] = lb[(o0 + (tid >> 4)) * RANK + (tid & 15)] * LORA_SCALE;
        else if (tid < 80) nf4s[tid - 64] = NF4_TAB[tid - 64];
        __syncthreads();

        #pragma unroll
        for (int it = 0; it < 2; ++it) {
            const int i0 = (it * 256 + tid) * 8;
            float w[4][8];
            #pragma unroll
            for (int oo = 0; oo < 4; ++oo) {
                const size_t base = (size_t)(o0 + oo) * IN_DIM + i0;
                i32x4 c0 = __builtin_nontemporal_load((const i32x4*)(codes + base));
                i32x4 c1 = __builtin_nontemporal_load((const i32x4*)(codes + base + 4));
                const float sc = scales[(o0 + oo) * (IN_DIM / 64) + (i0 >> 6)];
                w[oo][0] = nf4s[c0[0]] * sc; w[oo][1] = nf4s[c0[1]] * sc;
                w[oo][2] = nf4s[c0[2]] * sc; w[oo][3] = nf4s[c0[3]] * sc;
                w[oo][4] = nf4s[c1[0]] * sc; w[oo][5] = nf4s[c1[1]] * sc;
                w[oo][6] = nf4s[c1[2]] * sc; w[oo][7] = nf4s[c1[3]] * sc;
            }
            #pragma unroll
            for (int r = 0; r < RANK; ++r) {
                f32x4 a0 = *(const f32x4*)(la + r * IN_DIM + i0);
                f32x4 a1 = *(const f32x4*)(la + r * IN_DIM + i0 + 4);
                #pragma unroll
                for (int oo = 0; oo < 4; ++oo) {
                    const float b = lbs[oo][r];
                    w[oo][0] += b * a0[0]; w[oo][1] += b * a0[1];
                    w[oo][2] += b * a0[2]; w[oo][3] += b * a0[3];
                    w[oo][4] += b * a1[0]; w[oo][5] += b * a1[1];
                    w[oo][6] += b * a1[2]; w[oo][7] += b * a1[3];
                }
            }
            #pragma unroll
            for (int oo = 0; oo < 4; ++oo) {
                bf16x8 v;
                #pragma unroll
                for (int j = 0; j < 8; ++j) v[j] = (bf16_t)w[oo][j];
                *(bf16x8*)(W + (size_t)(o0 + oo) * IN_DIM + i0) = v;
            }
        }
    } else {
        const int bid = blockIdx.x - 1024;
        const int n8 = (M_TOK * IN_DIM) / 8;
        const int stride = 2048 * 256;
        for (int i = bid * 256 + tid; i < n8; i += stride) {
            const size_t e = (size_t)i * 8;
            f32x4 a = __builtin_nontemporal_load((const f32x4*)(x + e));
            f32x4 b = __builtin_nontemporal_load((const f32x4*)(x + e + 4));
            bf16x8 v;
            v[0] = (bf16_t)a[0]; v[1] = (bf16_t)a[1]; v[2] = (bf16_t)a[2]; v[3] = (bf16_t)a[3];
            v[4] = (bf16_t)b[0]; v[5] = (bf16_t)b[1]; v[6] = (bf16_t)b[2]; v[7] = (bf16_t)b[3];
            *(bf16x8*)(xb + e) = v;
        }
    }
}

// ---------------------------------------------------------------- GEMM
__global__ __launch_bounds__(512, 2) void gemm_bt(
    const bf16_t* __restrict__ A, const bf16_t* __restrict__ B,
    float* __restrict__ C)
{
    // [slot(2)][A|B][khalf(2)] 16KB regions = 128 KiB
    __shared__ __align__(128) char lds[131072];

    const int tid  = threadIdx.x;
    const int wave = tid >> 6;
    const int lane = tid & 63;

    const int flat = blockIdx.y * gridDim.x + blockIdx.x;     // 0..511
    const int swz  = (flat & 7) * 64 + (flat >> 3);           // XCD swizzle
    const int bx = swz & 15;
    const int by = swz >> 4;
    const int m0 = by * 256;
    const int n0 = bx * 256;

    const int wr = wave >> 2;         // 0..1
    const int wc = wave & 3;          // 0..3

    f32x4 acc[8][4];
    #pragma unroll
    for (int i = 0; i < 8; ++i)
        #pragma unroll
        for (int j = 0; j < 4; ++j) acc[i][j] = (f32x4)0.0f;

    const int frow = lane & 15;
    const int fch  = lane >> 4;
    const int fxor = (fch ^ ((frow >> 1) & 3)) << 4;   // R1-verified swizzle
    const int aoff = (wr * 128 + frow) * 64 + fxor;    // A frag f: +f*1024
    const int boff = (wc * 64  + frow) * 64 + fxor;    // B (nh,j): +nh*2048+j*1024

    // staging addressing: 2 x 16B per thread per 16KB region
    const int d0 = tid * 16, d1 = 8192 + tid * 16;
    const int sr0 = d0 >> 6, sr1 = d1 >> 6;
    const int sg0 = ((d0 >> 4) & 3) ^ ((sr0 >> 1) & 3);
    const int sg1 = ((d1 >> 4) & 3) ^ ((sr1 >> 1) & 3);
    const char* gA = (const char*)A;
    const char* gB = (const char*)B;

    bf16x8 fAe[8], fAo[8], fBe[2], fBo[2];

#define RD_A2(FA, SL, KH, J0) do {                                             \
    const char* b_ = lds + (SL) * 65536 + (KH) * 16384;                        \
    FA[(J0)]     = *(const bf16x8*)(b_ + aoff + (J0) * 1024);                  \
    FA[(J0) + 1] = *(const bf16x8*)(b_ + aoff + ((J0) + 1) * 1024);            \
} while (0)

#define RD_B(FB, SL, KH, NH) do {                                              \
    const char* b_ = lds + (SL) * 65536 + 32768 + (KH) * 16384;                \
    FB[0] = *(const bf16x8*)(b_ + boff + (NH) * 2048);                         \
    FB[1] = *(const bf16x8*)(b_ + boff + (NH) * 2048 + 1024);                  \
} while (0)

#define STG1(OPI, KH_, SL, T) do {                                             \
    const char* g_  = (OPI) ? gB : gA;                                         \
    const int   r0_ = (OPI) ? n0 : m0;                                         \
    const size_t ko_ = (size_t)(T) * 128 + (KH_) * 64;                         \
    const char* s0_ = g_ + (size_t)(r0_ + sr0) * 8192 + ko_ + (sg0 << 4);      \
    const char* s1_ = g_ + (size_t)(r0_ + sr1) * 8192 + ko_ + (sg1 << 4);      \
    char* db_ = lds + (SL) * 65536 + (OPI) * 32768 + (KH_) * 16384 + wave * 1024; \
    __builtin_amdgcn_global_load_lds(                                          \
        (const __attribute__((address_space(1))) void*)s0_,                    \
        (__attribute__((address_space(3))) void*)db_, 16, 0, 0);               \
    __builtin_amdgcn_global_load_lds(                                          \
        (const __attribute__((address_space(1))) void*)s1_,                    \
        (__attribute__((address_space(3))) void*)(db_ + 8192), 16, 0, 0);      \
} while (0)

#define MM4(FA, F0, FB, BI, NH) do {                                           \
    _Pragma("unroll")                                                          \
    for (int f_ = 0; f_ < 4; ++f_)                                             \
        acc[(F0) + f_][(NH) * 2 + (BI)] =                                      \
            __builtin_amdgcn_mfma_f32_16x16x32_bf16(                           \
                FA[(F0) + f_], FB[BI], acc[(F0) + f_][(NH) * 2 + (BI)], 0, 0, 0); \
} while (0)

// phase: one cluster {16 MFMA || 6 ds_read(next) || 1 STG}; NO lgkm drain;
// vmcnt(6) @odd-phase end certifies stages; ONE barrier per phase.
#define PHASE(SOP, SKH, SSL, ST, CHK, FA, FB, NH, RD1, RD2, RD3) do {          \
    __builtin_amdgcn_s_setprio(1);                                             \
    MM4(FA, 0, FB, 0, NH);                                                     \
    RD1;                                                                       \
    MM4(FA, 0, FB, 1, NH);                                                     \
    STG1(SOP, SKH, SSL, ST);                                                   \
    MM4(FA, 4, FB, 0, NH);                                                     \
    RD2;                                                                       \
    MM4(FA, 4, FB, 1, NH);                                                     \
    RD3;                                                                       \
    __builtin_amdgcn_s_setprio(0);                                             \
    if (CHK) { asm volatile("s_waitcnt vmcnt(6)" ::: "memory"); }              \
    __builtin_amdgcn_s_barrier();                                              \
} while (0)

    // ---- prologue: stage S0 all (t0), then S1 A_k0,B_k0,A_k1 (t1)
    STG1(0, 0, 0, 0); STG1(1, 0, 0, 0); STG1(0, 1, 0, 0); STG1(1, 1, 0, 0);
    STG1(0, 0, 1, 1); STG1(1, 0, 1, 1); STG1(0, 1, 1, 1);
    asm volatile("s_waitcnt vmcnt(6)" ::: "memory");   // S0 fully landed
    __builtin_amdgcn_s_barrier();
    RD_A2(fAe, 0, 0, 0); RD_A2(fAe, 0, 0, 2);
    RD_A2(fAe, 0, 0, 4); RD_A2(fAe, 0, 0, 6);
    RD_B(fBe, 0, 0, 0);

    // ---- main loop: iter i computes K-tiles X=2i (slot0), Y=2i+1 (slot1)
    for (int i = 0; i < 32; ++i) {
        const int tY  = 2 * i + 1;
        const int tS0 = (2 * i + 2) & 63;
        const int tS1 = (2 * i + 3) & 63;
        // P0: MM X(k0,n0)
        PHASE(1, 1, 1, tY,  0, fAe, fBe, 0,
              RD_A2(fAo, 0, 1, 0), RD_A2(fAo, 0, 1, 2), RD_B(fBo, 0, 0, 1));
        // P1: MM X(k0,n1)
        PHASE(0, 0, 0, tS0, 1, fAe, fBo, 1,
              RD_A2(fAo, 0, 1, 4), RD_A2(fAo, 0, 1, 6), RD_B(fBe, 0, 1, 0));
        // P2: MM X(k1,n0)
        PHASE(1, 0, 0, tS0, 0, fAo, fBe, 0,
              RD_A2(fAe, 1, 0, 0), RD_A2(fAe, 1, 0, 2), RD_B(fBo, 0, 1, 1));
        // P3: MM X(k1,n1)
        PHASE(0, 1, 0, tS0, 1, fAo, fBo, 1,
              RD_A2(fAe, 1, 0, 4), RD_A2(fAe, 1, 0, 6), RD_B(fBe, 1, 0, 0));
        // P4: MM Y(k0,n0)
        PHASE(1, 1, 0, tS0, 0, fAe, fBe, 0,
              RD_A2(fAo, 1, 1, 0), RD_A2(fAo, 1, 1, 2), RD_B(fBo, 1, 0, 1));
        // P5: MM Y(k0,n1)
        PHASE(0, 0, 1, tS1, 1, fAe, fBo, 1,
              RD_A2(fAo, 1, 1, 4), RD_A2(fAo, 1, 1, 6), RD_B(fBe, 1, 1, 0));
        // P6: MM Y(k1,n0)
        PHASE(1, 0, 1, tS1, 0, fAo, fBe, 0,
              RD_A2(fAe, 0, 0, 0), RD_A2(fAe, 0, 0, 2), RD_B(fBo, 1, 1, 1));
        // P7: MM Y(k1,n1)
        PHASE(0, 1, 1, tS1, 1, fAo, fBo, 1,
              RD_A2(fAe, 0, 0, 4), RD_A2(fAe, 0, 0, 6), RD_B(fBe, 0, 0, 0));
    }

    // ---- C write: D layout col=lane&15, row=(lane>>4)*4+reg [m89-verified]
    const int crow = (lane >> 4) * 4;
    const int ccol = lane & 15;
    #pragma unroll
    for (int i = 0; i < 8; ++i) {
        #pragma unroll
        for (int j = 0; j < 4; ++j) {
            const int mb = m0 + wr * 128 + i * 16 + crow;
            const int nb = n0 + wc * 64 + j * 16 + ccol;
            #pragma unroll
            for (int r = 0; r < 4; ++r)
                C[(size_t)(mb + r) * OUT_DIM + nb] = acc[i][j][r];
        }
    }
#undef RD_A2
#undef RD_B
#undef STG1
#undef MM4
#undef PHASE
}

// ---------------------------------------------------------------- launch
extern "C" void kernel_launch(void* const* d_in, const int* in_sizes, int n_in,
                              void* d_out, int out_size, void* d_ws, size_t ws_size,
                              hipStream_t stream) {
    const float* x      = (const float*)d_in[0];
    const int*   codes  = (const int*)d_in[1];
    const float* scales = (const float*)d_in[2];
    const float* la     = (const float*)d_in[3];
    const float* lb     = (const float*)d_in[4];
    float* out = (float*)d_out;

    bf16_t* W  = (bf16_t*)d_ws;
    bf16_t* xb = (bf16_t*)((char*)d_ws + (size_t)OUT_DIM * IN_DIM * 2);

    prep_all<<<1024 + 2048, 256, 0, stream>>>(x, codes, scales, la, lb, W, xb);

    dim3 grid(OUT_DIM / 256, M_TOK / 256);   // (16, 32) = 512 blocks
    gemm_bt<<<grid, 512, 0, stream>>>(xb, W, out);
}

// Round 17
// 283.160 us; speedup vs baseline: 1.0509x; 1.0010x over previous
//
#include <hip/hip_runtime.h>
#include <hip/hip_bf16.h>

// LoRALinear with NF4 base: out = x @ W^T + (alpha/rank) * (x@A^T)@B^T
//  Fold: W_eff[o][i] = NF4[codes[o][i]] * scales[o][i/64] + 2 * sum_r B[o][r]*A[r][i]
//  One bf16 GEMM: out[M=8192][N=4096] = xb[M][K=4096] . W_eff[N][K]^T
//
// GEMM: R9 structure — measured optimum (216us, 1274 TF, MfmaUtil 61.6%,
// 0 conflicts). 256x256 tile, BK=64, 8 phases, 16x16x32 MFMA, next-phase
// reads interleaved into the MFMA cluster (E/O reg sets), 1 STG/phase, ONE
// barrier/phase, compiler-counted lgkm waits, vmcnt(6) at odd-phase ends.
// This round's single variable: s_setprio REMOVED (m190: setprio hurts on
// barrier-lockstep GEMM schedules; never isolated on this kernel).

#define IN_DIM  4096
#define OUT_DIM 4096
#define RANK    16
#define M_TOK   8192
#define LORA_SCALE 2.0f

typedef __bf16 bf16_t;
typedef bf16_t bf16x8 __attribute__((ext_vector_type(8)));
typedef float  f32x4  __attribute__((ext_vector_type(4)));

__device__ __constant__ float NF4_TAB[16] = {
    -1.0f, -0.6961928009986877f, -0.5250730514526367f, -0.39491748809814453f,
    -0.28444138169288635f, -0.18477343022823334f, -0.09105003625154495f, 0.0f,
    0.07958029955625534f, 0.16093020141124725f, 0.24611230194568634f,
    0.33791524171829224f, 0.44070982933044434f, 0.5626170039176941f,
    0.7229568362236328f, 1.0f};

// ------------------------------------------- prep W_eff + cast x (merged)
__global__ __launch_bounds__(256) void prep_all(
    const float* __restrict__ x,
    const int* __restrict__ codes, const float* __restrict__ scales,
    const float* __restrict__ la, const float* __restrict__ lb,
    bf16_t* __restrict__ W, bf16_t* __restrict__ xb)
{
    const int tid = threadIdx.x;
    if (blockIdx.x < 1024) {
        __shared__ float nf4s[16];
        __shared__ float lbs[4][16];
        const int o0 = blockIdx.x * 4;
        if (tid < 64) lbs[tid >> 4][tid & 15] = lb[(o0 + (tid >> 4)) * RANK + (tid & 15)] * LORA_SCALE;
        else if (tid < 80) nf4s[tid - 64] = NF4_TAB[tid - 64];
        __syncthreads();

        #pragma unroll
        for (int it = 0; it < 2; ++it) {
            const int i0 = (it * 256 + tid) * 8;
            float w[4][8];
            #pragma unroll
            for (int oo = 0; oo < 4; ++oo) {
                const size_t base = (size_t)(o0 + oo) * IN_DIM + i0;
                int4 c0 = *(const int4*)(codes + base);
                int4 c1 = *(const int4*)(codes + base + 4);
                const float sc = scales[(o0 + oo) * (IN_DIM / 64) + (i0 >> 6)];
                w[oo][0] = nf4s[c0.x] * sc; w[oo][1] = nf4s[c0.y] * sc;
                w[oo][2] = nf4s[c0.z] * sc; w[oo][3] = nf4s[c0.w] * sc;
                w[oo][4] = nf4s[c1.x] * sc; w[oo][5] = nf4s[c1.y] * sc;
                w[oo][6] = nf4s[c1.z] * sc; w[oo][7] = nf4s[c1.w] * sc;
            }
            #pragma unroll
            for (int r = 0; r < RANK; ++r) {
                float4 a0 = *(const float4*)(la + r * IN_DIM + i0);
                float4 a1 = *(const float4*)(la + r * IN_DIM + i0 + 4);
                #pragma unroll
                for (int oo = 0; oo < 4; ++oo) {
                    const float b = lbs[oo][r];
                    w[oo][0] += b * a0.x; w[oo][1] += b * a0.y;
                    w[oo][2] += b * a0.z; w[oo][3] += b * a0.w;
                    w[oo][4] += b * a1.x; w[oo][5] += b * a1.y;
                    w[oo][6] += b * a1.z; w[oo][7] += b * a1.w;
                }
            }
            #pragma unroll
            for (int oo = 0; oo < 4; ++oo) {
                bf16x8 v;
                #pragma unroll
                for (int j = 0; j < 8; ++j) v[j] = (bf16_t)w[oo][j];
                *(bf16x8*)(W + (size_t)(o0 + oo) * IN_DIM + i0) = v;
            }
        }
    } else {
        const int bid = blockIdx.x - 1024;
        const int n8 = (M_TOK * IN_DIM) / 8;
        const int stride = 2048 * 256;
        for (int i = bid * 256 + tid; i < n8; i += stride) {
            const size_t e = (size_t)i * 8;
            float4 a = *(const float4*)(x + e);
            float4 b = *(const float4*)(x + e + 4);
            bf16x8 v;
            v[0] = (bf16_t)a.x; v[1] = (bf16_t)a.y; v[2] = (bf16_t)a.z; v[3] = (bf16_t)a.w;
            v[4] = (bf16_t)b.x; v[5] = (bf16_t)b.y; v[6] = (bf16_t)b.z; v[7] = (bf16_t)b.w;
            *(bf16x8*)(xb + e) = v;
        }
    }
}

// ---------------------------------------------------------------- GEMM
__global__ __launch_bounds__(512, 2) void gemm_bt(
    const bf16_t* __restrict__ A, const bf16_t* __restrict__ B,
    float* __restrict__ C)
{
    // [slot(2)][A|B][khalf(2)] 16KB regions = 128 KiB
    __shared__ __align__(128) char lds[131072];

    const int tid  = threadIdx.x;
    const int wave = tid >> 6;
    const int lane = tid & 63;

    const int flat = blockIdx.y * gridDim.x + blockIdx.x;     // 0..511
    const int swz  = (flat & 7) * 64 + (flat >> 3);           // XCD swizzle
    const int bx = swz & 15;
    const int by = swz >> 4;
    const int m0 = by * 256;
    const int n0 = bx * 256;

    const int wr = wave >> 2;         // 0..1
    const int wc = wave & 3;          // 0..3

    f32x4 acc[8][4];
    #pragma unroll
    for (int i = 0; i < 8; ++i)
        #pragma unroll
        for (int j = 0; j < 4; ++j) acc[i][j] = (f32x4)0.0f;

    const int frow = lane & 15;
    const int fch  = lane >> 4;
    const int fxor = (fch ^ ((frow >> 1) & 3)) << 4;   // R1-verified swizzle
    const int aoff = (wr * 128 + frow) * 64 + fxor;    // A frag f: +f*1024
    const int boff = (wc * 64  + frow) * 64 + fxor;    // B (nh,j): +nh*2048+j*1024

    // staging addressing: 2 x 16B per thread per 16KB region
    const int d0 = tid * 16, d1 = 8192 + tid * 16;
    const int sr0 = d0 >> 6, sr1 = d1 >> 6;
    const int sg0 = ((d0 >> 4) & 3) ^ ((sr0 >> 1) & 3);
    const int sg1 = ((d1 >> 4) & 3) ^ ((sr1 >> 1) & 3);
    const char* gA = (const char*)A;
    const char* gB = (const char*)B;

    bf16x8 fAe[8], fAo[8], fBe[2], fBo[2];

#define RD_A2(FA, SL, KH, J0) do {                                             \
    const char* b_ = lds + (SL) * 65536 + (KH) * 16384;                        \
    FA[(J0)]     = *(const bf16x8*)(b_ + aoff + (J0) * 1024);                  \
    FA[(J0) + 1] = *(const bf16x8*)(b_ + aoff + ((J0) + 1) * 1024);            \
} while (0)

#define RD_B(FB, SL, KH, NH) do {                                              \
    const char* b_ = lds + (SL) * 65536 + 32768 + (KH) * 16384;                \
    FB[0] = *(const bf16x8*)(b_ + boff + (NH) * 2048);                         \
    FB[1] = *(const bf16x8*)(b_ + boff + (NH) * 2048 + 1024);                  \
} while (0)

#define STG1(OPI, KH_, SL, T) do {                                             \
    const char* g_  = (OPI) ? gB : gA;                                         \
    const int   r0_ = (OPI) ? n0 : m0;                                         \
    const size_t ko_ = (size_t)(T) * 128 + (KH_) * 64;                         \
    const char* s0_ = g_ + (size_t)(r0_ + sr0) * 8192 + ko_ + (sg0 << 4);      \
    const char* s1_ = g_ + (size_t)(r0_ + sr1) * 8192 + ko_ + (sg1 << 4);      \
    char* db_ = lds + (SL) * 65536 + (OPI) * 32768 + (KH_) * 16384 + wave * 1024; \
    __builtin_amdgcn_global_load_lds(                                          \
        (const __attribute__((address_space(1))) void*)s0_,                    \
        (__attribute__((address_space(3))) void*)db_, 16, 0, 0);               \
    __builtin_amdgcn_global_load_lds(                                          \
        (const __attribute__((address_space(1))) void*)s1_,                    \
        (__attribute__((address_space(3))) void*)(db_ + 8192), 16, 0, 0);      \
} while (0)

#define MM4(FA, F0, FB, BI, NH) do {                                           \
    _Pragma("unroll")                                                          \
    for (int f_ = 0; f_ < 4; ++f_)                                             \
        acc[(F0) + f_][(NH) * 2 + (BI)] =                                      \
            __builtin_amdgcn_mfma_f32_16x16x32_bf16(                           \
                FA[(F0) + f_], FB[BI], acc[(F0) + f_][(NH) * 2 + (BI)], 0, 0, 0); \
} while (0)

// phase: one cluster {16 MFMA || 6 ds_read(next) || 1 STG}; NO lgkm drain;
// vmcnt(6) @odd-phase end certifies stages; ONE barrier per phase.
// setprio removed this round (single-variable A/B vs R9).
#define PHASE(SOP, SKH, SSL, ST, CHK, FA, FB, NH, RD1, RD2, RD3) do {          \
    MM4(FA, 0, FB, 0, NH);                                                     \
    RD1;                                                                       \
    MM4(FA, 0, FB, 1, NH);                                                     \
    STG1(SOP, SKH, SSL, ST);                                                   \
    MM4(FA, 4, FB, 0, NH);                                                     \
    RD2;                                                                       \
    MM4(FA, 4, FB, 1, NH);                                                     \
    RD3;                                                                       \
    if (CHK) { asm volatile("s_waitcnt vmcnt(6)" ::: "memory"); }              \
    __builtin_amdgcn_s_barrier();                                              \
} while (0)

    // ---- prologue: stage S0 all (t0), then S1 A_k0,B_k0,A_k1 (t1)
    STG1(0, 0, 0, 0); STG1(1, 0, 0, 0); STG1(0, 1, 0, 0); STG1(1, 1, 0, 0);
    STG1(0, 0, 1, 1); STG1(1, 0, 1, 1); STG1(0, 1, 1, 1);
    asm volatile("s_waitcnt vmcnt(6)" ::: "memory");   // S0 fully landed
    __builtin_amdgcn_s_barrier();
    RD_A2(fAe, 0, 0, 0); RD_A2(fAe, 0, 0, 2);
    RD_A2(fAe, 0, 0, 4); RD_A2(fAe, 0, 0, 6);
    RD_B(fBe, 0, 0, 0);

    // ---- main loop: iter i computes K-tiles X=2i (slot0), Y=2i+1 (slot1)
    for (int i = 0; i < 32; ++i) {
        const int tY  = 2 * i + 1;
        const int tS0 = (2 * i + 2) & 63;
        const int tS1 = (2 * i + 3) & 63;
        // P0: MM X(k0,n0)
        PHASE(1, 1, 1, tY,  0, fAe, fBe, 0,
              RD_A2(fAo, 0, 1, 0), RD_A2(fAo, 0, 1, 2), RD_B(fBo, 0, 0, 1));
        // P1: MM X(k0,n1)
        PHASE(0, 0, 0, tS0, 1, fAe, fBo, 1,
              RD_A2(fAo, 0, 1, 4), RD_A2(fAo, 0, 1, 6), RD_B(fBe, 0, 1, 0));
        // P2: MM X(k1,n0)
        PHASE(1, 0, 0, tS0, 0, fAo, fBe, 0,
              RD_A2(fAe, 1, 0, 0), RD_A2(fAe, 1, 0, 2), RD_B(fBo, 0, 1, 1));
        // P3: MM X(k1,n1)
        PHASE(0, 1, 0, tS0, 1, fAo, fBo, 1,
              RD_A2(fAe, 1, 0, 4), RD_A2(fAe, 1, 0, 6), RD_B(fBe, 1, 0, 0));
        // P4: MM Y(k0,n0)
        PHASE(1, 1, 0, tS0, 0, fAe, fBe, 0,
              RD_A2(fAo, 1, 1, 0), RD_A2(fAo, 1, 1, 2), RD_B(fBo, 1, 0, 1));
        // P5: MM Y(k0,n1)
        PHASE(0, 0, 1, tS1, 1, fAe, fBo, 1,
              RD_A2(fAo, 1, 1, 4), RD_A2(fAo, 1, 1, 6), RD_B(fBe, 1, 1, 0));
        // P6: MM Y(k1,n0)
        PHASE(1, 0, 1, tS1, 0, fAo, fBe, 0,
              RD_A2(fAe, 0, 0, 0), RD_A2(fAe, 0, 0, 2), RD_B(fBo, 1, 1, 1));
        // P7: MM Y(k1,n1)
        PHASE(0, 1, 1, tS1, 1, fAo, fBo, 1,
              RD_A2(fAe, 0, 0, 4), RD_A2(fAe, 0, 0, 6), RD_B(fBe, 0, 0, 0));
    }

    // ---- C write: D layout col=lane&15, row=(lane>>4)*4+reg [m89-verified]
    const int crow = (lane >> 4) * 4;
    const int ccol = lane & 15;
    #pragma unroll
    for (int i = 0; i < 8; ++i) {
        #pragma unroll
        for (int j = 0; j < 4; ++j) {
            const int mb = m0 + wr * 128 + i * 16 + crow;
            const int nb = n0 + wc * 64 + j * 16 + ccol;
            #pragma unroll
            for (int r = 0; r < 4; ++r)
                C[(size_t)(mb + r) * OUT_DIM + nb] = acc[i][j][r];
        }
    }
#undef RD_A2
#undef RD_B
#undef STG1
#undef MM4
#undef PHASE
}

// ---------------------------------------------------------------- launch
extern "C" void kernel_launch(void* const* d_in, const int* in_sizes, int n_in,
                              void* d_out, int out_size, void* d_ws, size_t ws_size,
                              hipStream_t stream) {
    const float* x      = (const float*)d_in[0];
    const int*   codes  = (const int*)d_in[1];
    const float* scales = (const float*)d_in[2];
    const float* la     = (const float*)d_in[3];
    const float* lb     = (const float*)d_in[4];
    float* out = (float*)d_out;

    bf16_t* W  = (bf16_t*)d_ws;
    bf16_t* xb = (bf16_t*)((char*)d_ws + (size_t)OUT_DIM * IN_DIM * 2);

    prep_all<<<1024 + 2048, 256, 0, stream>>>(x, codes, scales, la, lb, W, xb);

    dim3 grid(OUT_DIM / 256, M_TOK / 256);   // (16, 32) = 512 blocks
    gemm_bt<<<grid, 512, 0, stream>>>(xb, W, out);
}

// Round 18
// 281.667 us; speedup vs baseline: 1.0565x; 1.0053x over previous
//
#include <hip/hip_runtime.h>
#include <hip/hip_bf16.h>

// LoRALinear with NF4 base: out = x @ W^T + (alpha/rank) * (x@A^T)@B^T
//  Fold: W_eff[o][i] = NF4[codes[o][i]] * scales[o][i/64] + 2 * sum_r B[o][r]*A[r][i]
//  One bf16 GEMM: out[M=8192][N=4096] = xb[M][K=4096] . W_eff[N][K]^T
//
// FINAL: R9 configuration — measured optimum (280.8us total / 216us GEMM,
// 1274 TF, MfmaUtil 61.6%, 0 bank conflicts; reproduced R9+R15).
// 256x256 tile, BK=64, 8 phases, 16x16x32 MFMA, next-phase reads
// interleaved into the MFMA cluster (E/O reg sets), setprio(1) around the
// cluster (R16 A/B: removal costs 1.3%), 1 STG/phase, ONE barrier/phase,
// compiler-counted lgkm waits, vmcnt(6) at odd-phase ends.
// Neighborhood fully mapped R4-R16; all other arms regressed or null.

#define IN_DIM  4096
#define OUT_DIM 4096
#define RANK    16
#define M_TOK   8192
#define LORA_SCALE 2.0f

typedef __bf16 bf16_t;
typedef bf16_t bf16x8 __attribute__((ext_vector_type(8)));
typedef float  f32x4  __attribute__((ext_vector_type(4)));

__device__ __constant__ float NF4_TAB[16] = {
    -1.0f, -0.6961928009986877f, -0.5250730514526367f, -0.39491748809814453f,
    -0.28444138169288635f, -0.18477343022823334f, -0.09105003625154495f, 0.0f,
    0.07958029955625534f, 0.16093020141124725f, 0.24611230194568634f,
    0.33791524171829224f, 0.44070982933044434f, 0.5626170039176941f,
    0.7229568362236328f, 1.0f};

// ------------------------------------------- prep W_eff + cast x (merged)
__global__ __launch_bounds__(256) void prep_all(
    const float* __restrict__ x,
    const int* __restrict__ codes, const float* __restrict__ scales,
    const float* __restrict__ la, const float* __restrict__ lb,
    bf16_t* __restrict__ W, bf16_t* __restrict__ xb)
{
    const int tid = threadIdx.x;
    if (blockIdx.x < 1024) {
        __shared__ float nf4s[16];
        __shared__ float lbs[4][16];
        const int o0 = blockIdx.x * 4;
        if (tid < 64) lbs[tid >> 4][tid & 15] = lb[(o0 + (tid >> 4)) * RANK + (tid & 15)] * LORA_SCALE;
        else if (tid < 80) nf4s[tid - 64] = NF4_TAB[tid - 64];
        __syncthreads();

        #pragma unroll
        for (int it = 0; it < 2; ++it) {
            const int i0 = (it * 256 + tid) * 8;
            float w[4][8];
            #pragma unroll
            for (int oo = 0; oo < 4; ++oo) {
                const size_t base = (size_t)(o0 + oo) * IN_DIM + i0;
                int4 c0 = *(const int4*)(codes + base);
                int4 c1 = *(const int4*)(codes + base + 4);
                const float sc = scales[(o0 + oo) * (IN_DIM / 64) + (i0 >> 6)];
                w[oo][0] = nf4s[c0.x] * sc; w[oo][1] = nf4s[c0.y] * sc;
                w[oo][2] = nf4s[c0.z] * sc; w[oo][3] = nf4s[c0.w] * sc;
                w[oo][4] = nf4s[c1.x] * sc; w[oo][5] = nf4s[c1.y] * sc;
                w[oo][6] = nf4s[c1.z] * sc; w[oo][7] = nf4s[c1.w] * sc;
            }
            #pragma unroll
            for (int r = 0; r < RANK; ++r) {
                float4 a0 = *(const float4*)(la + r * IN_DIM + i0);
                float4 a1 = *(const float4*)(la + r * IN_DIM + i0 + 4);
                #pragma unroll
                for (int oo = 0; oo < 4; ++oo) {
                    const float b = lbs[oo][r];
                    w[oo][0] += b * a0.x; w[oo][1] += b * a0.y;
                    w[oo][2] += b * a0.z; w[oo][3] += b * a0.w;
                    w[oo][4] += b * a1.x; w[oo][5] += b * a1.y;
                    w[oo][6] += b * a1.z; w[oo][7] += b * a1.w;
                }
            }
            #pragma unroll
            for (int oo = 0; oo < 4; ++oo) {
                bf16x8 v;
                #pragma unroll
                for (int j = 0; j < 8; ++j) v[j] = (bf16_t)w[oo][j];
                *(bf16x8*)(W + (size_t)(o0 + oo) * IN_DIM + i0) = v;
            }
        }
    } else {
        const int bid = blockIdx.x - 1024;
        const int n8 = (M_TOK * IN_DIM) / 8;
        const int stride = 2048 * 256;
        for (int i = bid * 256 + tid; i < n8; i += stride) {
            const size_t e = (size_t)i * 8;
            float4 a = *(const float4*)(x + e);
            float4 b = *(const float4*)(x + e + 4);
            bf16x8 v;
            v[0] = (bf16_t)a.x; v[1] = (bf16_t)a.y; v[2] = (bf16_t)a.z; v[3] = (bf16_t)a.w;
            v[4] = (bf16_t)b.x; v[5] = (bf16_t)b.y; v[6] = (bf16_t)b.z; v[7] = (bf16_t)b.w;
            *(bf16x8*)(xb + e) = v;
        }
    }
}

// ---------------------------------------------------------------- GEMM
__global__ __launch_bounds__(512, 2) void gemm_bt(
    const bf16_t* __restrict__ A, const bf16_t* __restrict__ B,
    float* __restrict__ C)
{
    // [slot(2)][A|B][khalf(2)] 16KB regions = 128 KiB
    __shared__ __align__(128) char lds[131072];

    const int tid  = threadIdx.x;
    const int wave = tid >> 6;
    const int lane = tid & 63;

    const int flat = blockIdx.y * gridDim.x + blockIdx.x;     // 0..511
    const int swz  = (flat & 7) * 64 + (flat >> 3);           // XCD swizzle
    const int bx = swz & 15;
    const int by = swz >> 4;
    const int m0 = by * 256;
    const int n0 = bx * 256;

    const int wr = wave >> 2;         // 0..1
    const int wc = wave & 3;          // 0..3

    f32x4 acc[8][4];
    #pragma unroll
    for (int i = 0; i < 8; ++i)
        #pragma unroll
        for (int j = 0; j < 4; ++j) acc[i][j] = (f32x4)0.0f;

    const int frow = lane & 15;
    const int fch  = lane >> 4;
    const int fxor = (fch ^ ((frow >> 1) & 3)) << 4;   // R1-verified swizzle
    const int aoff = (wr * 128 + frow) * 64 + fxor;    // A frag f: +f*1024
    const int boff = (wc * 64  + frow) * 64 + fxor;    // B (nh,j): +nh*2048+j*1024

    // staging addressing: 2 x 16B per thread per 16KB region
    const int d0 = tid * 16, d1 = 8192 + tid * 16;
    const int sr0 = d0 >> 6, sr1 = d1 >> 6;
    const int sg0 = ((d0 >> 4) & 3) ^ ((sr0 >> 1) & 3);
    const int sg1 = ((d1 >> 4) & 3) ^ ((sr1 >> 1) & 3);
    const char* gA = (const char*)A;
    const char* gB = (const char*)B;

    bf16x8 fAe[8], fAo[8], fBe[2], fBo[2];

#define RD_A2(FA, SL, KH, J0) do {                                             \
    const char* b_ = lds + (SL) * 65536 + (KH) * 16384;                        \
    FA[(J0)]     = *(const bf16x8*)(b_ + aoff + (J0) * 1024);                  \
    FA[(J0) + 1] = *(const bf16x8*)(b_ + aoff + ((J0) + 1) * 1024);            \
} while (0)

#define RD_B(FB, SL, KH, NH) do {                                              \
    const char* b_ = lds + (SL) * 65536 + 32768 + (KH) * 16384;                \
    FB[0] = *(const bf16x8*)(b_ + boff + (NH) * 2048);                         \
    FB[1] = *(const bf16x8*)(b_ + boff + (NH) * 2048 + 1024);                  \
} while (0)

#define STG1(OPI, KH_, SL, T) do {                                             \
    const char* g_  = (OPI) ? gB : gA;                                         \
    const int   r0_ = (OPI) ? n0 : m0;                                         \
    const size_t ko_ = (size_t)(T) * 128 + (KH_) * 64;                         \
    const char* s0_ = g_ + (size_t)(r0_ + sr0) * 8192 + ko_ + (sg0 << 4);      \
    const char* s1_ = g_ + (size_t)(r0_ + sr1) * 8192 + ko_ + (sg1 << 4);      \
    char* db_ = lds + (SL) * 65536 + (OPI) * 32768 + (KH_) * 16384 + wave * 1024; \
    __builtin_amdgcn_global_load_lds(                                          \
        (const __attribute__((address_space(1))) void*)s0_,                    \
        (__attribute__((address_space(3))) void*)db_, 16, 0, 0);               \
    __builtin_amdgcn_global_load_lds(                                          \
        (const __attribute__((address_space(1))) void*)s1_,                    \
        (__attribute__((address_space(3))) void*)(db_ + 8192), 16, 0, 0);      \
} while (0)

#define MM4(FA, F0, FB, BI, NH) do {                                           \
    _Pragma("unroll")                                                          \
    for (int f_ = 0; f_ < 4; ++f_)                                             \
        acc[(F0) + f_][(NH) * 2 + (BI)] =                                      \
            __builtin_amdgcn_mfma_f32_16x16x32_bf16(                           \
                FA[(F0) + f_], FB[BI], acc[(F0) + f_][(NH) * 2 + (BI)], 0, 0, 0); \
} while (0)

// phase: one cluster {16 MFMA || 6 ds_read(next) || 1 STG}; NO lgkm drain;
// vmcnt(6) @odd-phase end certifies stages; ONE barrier per phase.
#define PHASE(SOP, SKH, SSL, ST, CHK, FA, FB, NH, RD1, RD2, RD3) do {          \
    __builtin_amdgcn_s_setprio(1);                                             \
    MM4(FA, 0, FB, 0, NH);                                                     \
    RD1;                                                                       \
    MM4(FA, 0, FB, 1, NH);                                                     \
    STG1(SOP, SKH, SSL, ST);                                                   \
    MM4(FA, 4, FB, 0, NH);                                                     \
    RD2;                                                                       \
    MM4(FA, 4, FB, 1, NH);                                                     \
    RD3;                                                                       \
    __builtin_amdgcn_s_setprio(0);                                             \
    if (CHK) { asm volatile("s_waitcnt vmcnt(6)" ::: "memory"); }              \
    __builtin_amdgcn_s_barrier();                                              \
} while (0)

    // ---- prologue: stage S0 all (t0), then S1 A_k0,B_k0,A_k1 (t1)
    STG1(0, 0, 0, 0); STG1(1, 0, 0, 0); STG1(0, 1, 0, 0); STG1(1, 1, 0, 0);
    STG1(0, 0, 1, 1); STG1(1, 0, 1, 1); STG1(0, 1, 1, 1);
    asm volatile("s_waitcnt vmcnt(6)" ::: "memory");   // S0 fully landed
    __builtin_amdgcn_s_barrier();
    RD_A2(fAe, 0, 0, 0); RD_A2(fAe, 0, 0, 2);
    RD_A2(fAe, 0, 0, 4); RD_A2(fAe, 0, 0, 6);
    RD_B(fBe, 0, 0, 0);

    // ---- main loop: iter i computes K-tiles X=2i (slot0), Y=2i+1 (slot1)
    for (int i = 0; i < 32; ++i) {
        const int tY  = 2 * i + 1;
        const int tS0 = (2 * i + 2) & 63;
        const int tS1 = (2 * i + 3) & 63;
        // P0: MM X(k0,n0)
        PHASE(1, 1, 1, tY,  0, fAe, fBe, 0,
              RD_A2(fAo, 0, 1, 0), RD_A2(fAo, 0, 1, 2), RD_B(fBo, 0, 0, 1));
        // P1: MM X(k0,n1)
        PHASE(0, 0, 0, tS0, 1, fAe, fBo, 1,
              RD_A2(fAo, 0, 1, 4), RD_A2(fAo, 0, 1, 6), RD_B(fBe, 0, 1, 0));
        // P2: MM X(k1,n0)
        PHASE(1, 0, 0, tS0, 0, fAo, fBe, 0,
              RD_A2(fAe, 1, 0, 0), RD_A2(fAe, 1, 0, 2), RD_B(fBo, 0, 1, 1));
        // P3: MM X(k1,n1)
        PHASE(0, 1, 0, tS0, 1, fAo, fBo, 1,
              RD_A2(fAe, 1, 0, 4), RD_A2(fAe, 1, 0, 6), RD_B(fBe, 1, 0, 0));
        // P4: MM Y(k0,n0)
        PHASE(1, 1, 0, tS0, 0, fAe, fBe, 0,
              RD_A2(fAo, 1, 1, 0), RD_A2(fAo, 1, 1, 2), RD_B(fBo, 1, 0, 1));
        // P5: MM Y(k0,n1)
        PHASE(0, 0, 1, tS1, 1, fAe, fBo, 1,
              RD_A2(fAo, 1, 1, 4), RD_A2(fAo, 1, 1, 6), RD_B(fBe, 1, 1, 0));
        // P6: MM Y(k1,n0)
        PHASE(1, 0, 1, tS1, 0, fAo, fBe, 0,
              RD_A2(fAe, 0, 0, 0), RD_A2(fAe, 0, 0, 2), RD_B(fBo, 1, 1, 1));
        // P7: MM Y(k1,n1)
        PHASE(0, 1, 1, tS1, 1, fAo, fBo, 1,
              RD_A2(fAe, 0, 0, 4), RD_A2(fAe, 0, 0, 6), RD_B(fBe, 0, 0, 0));
    }

    // ---- C write: D layout col=lane&15, row=(lane>>4)*4+reg [m89-verified]
    const int crow = (lane >> 4) * 4;
    const int ccol = lane & 15;
    #pragma unroll
    for (int i = 0; i < 8; ++i) {
        #pragma unroll
        for (int j = 0; j < 4; ++j) {
            const int mb = m0 + wr * 128 + i * 16 + crow;
            const int nb = n0 + wc * 64 + j * 16 + ccol;
            #pragma unroll
            for (int r = 0; r < 4; ++r)
                C[(size_t)(mb + r) * OUT_DIM + nb] = acc[i][j][r];
        }
    }
#undef RD_A2
#undef RD_B
#undef STG1
#undef MM4
#undef PHASE
}

// ---------------------------------------------------------------- launch
extern "C" void kernel_launch(void* const* d_in, const int* in_sizes, int n_in,
                              void* d_out, int out_size, void* d_ws, size_t ws_size,
                              hipStream_t stream) {
    const float* x      = (const float*)d_in[0];
    const int*   codes  = (const int*)d_in[1];
    const float* scales = (const float*)d_in[2];
    const float* la     = (const float*)d_in[3];
    const float* lb     = (const float*)d_in[4];
    float* out = (float*)d_out;

    bf16_t* W  = (bf16_t*)d_ws;
    bf16_t* xb = (bf16_t*)((char*)d_ws + (size_t)OUT_DIM * IN_DIM * 2);

    prep_all<<<1024 + 2048, 256, 0, stream>>>(x, codes, scales, la, lb, W, xb);

    dim3 grid(OUT_DIM / 256, M_TOK / 256);   // (16, 32) = 512 blocks
    gemm_bt<<<grid, 512, 0, stream>>>(xb, W, out);
}